// Round 4
// baseline (347.639 us; speedup 1.0000x reference)
//
#include <hip/hip_runtime.h>
#include <hip/hip_cooperative_groups.h>

namespace cg = cooperative_groups;

// GraphPooling: B=8, N=3072, D=1024, POOL=3, steps=1024
//  out[b, 2k,   d] = (sum x[b, s..e, d]) / (e-s+1) + 0.006
//  out[b, 2k+1, d] = mean(x[b, 3k:3k+3, d])
//
// Round-11: single cooperative fused kernel (R-scheme, same numerics as R3).
//  Theory: ~70 us of the 195 us total is unaccounted by DRAM traffic and
//  insensitive to traffic rebalancing -> suspect launch gaps/tails between
//  the 3 kernels. Fuse with grid.sync(). Side benefit: the fused kernel
//  (~100 us) finally exceeds the 62 us poison-fills and shows up in the
//  top-5 rocprof rows with real FETCH/WRITE/occupancy counters.
//  Phases (identical math to R3):
//   P1: per-chunk: 24 nt x-loads -> window means (out odd rows, nt store),
//       per-row exclusive prefix R, chunk total P.   [2 chunks/block]
//   P2: 2-level scan of P -> exclusive chunk prefix O (blocks bx<8 only).
//   P3: seg means: C[n] = O[n/24] + R[n]; 16 steps/block in 4 groups of 4.

constexpr int Bdim  = 8;
constexpr int Nn    = 3072;
constexpr int Dd    = 1024;
constexpr int STEPS = 1024;   // windows
constexpr int CHW   = 8;      // windows per chunk
constexpr int CHR   = 24;     // rows per chunk
constexpr int NCH   = 128;    // STEPS / CHW
constexpr int D4    = Dd / 4; // 256 float4 per row
constexpr float EPS = 0.006f;

constexpr size_t R_E = (size_t)Bdim * Nn * Dd;            // 96 MB (floats)
constexpr size_t P_E = (size_t)Bdim * NCH * Dd;           //  4 MB

typedef float nat_f4 __attribute__((ext_vector_type(4)));

__device__ __forceinline__ float4 f4add(float4 a, float4 b) {
    return make_float4(a.x + b.x, a.y + b.y, a.z + b.z, a.w + b.w);
}

__device__ __forceinline__ float4 f4sel(bool c, float4 a, float4 b) {
    return make_float4(c ? a.x : b.x, c ? a.y : b.y,
                       c ? a.z : b.z, c ? a.w : b.w);
}

__device__ __forceinline__ void nt_store(float4 v, float4* p) {
    nat_f4 nv = {v.x, v.y, v.z, v.w};
    __builtin_nontemporal_store(nv, reinterpret_cast<nat_f4*>(p));
}

__device__ __forceinline__ float4 nt_load(const float4* p) {
    nat_f4 nv = __builtin_nontemporal_load(reinterpret_cast<const nat_f4*>(p));
    return make_float4(nv.x, nv.y, nv.z, nv.w);
}

__global__ __launch_bounds__(256, 2)
void fused(const float4* __restrict__ x4, const int* __restrict__ graph,
           float4* __restrict__ out4, float4* __restrict__ R4,
           float4* __restrict__ P4, float4* __restrict__ O4) {
    const int t  = threadIdx.x;          // float4 column 0..255
    const int bx = blockIdx.x;           // 0..63
    const int b  = blockIdx.y;           // 0..7
    const float4 z4 = make_float4(0.f, 0.f, 0.f, 0.f);

    // ---------------- Phase 1: two chunks per block ----------------
    float4* opb = out4 + ((size_t)b * 2 * STEPS) * D4 + t;
#pragma unroll
    for (int cc = 0; cc < 2; ++cc) {
        const int ch = bx * 2 + cc;
        const int k0 = ch * CHW;
        const int r0 = ch * CHR;
        const float4* xp = x4 + ((size_t)(b * Nn + r0)) * D4 + t;
        float4*       rl = R4 + ((size_t)(b * Nn + r0)) * D4 + t;

        float4 v[CHR];
#pragma unroll
        for (int i = 0; i < CHR; ++i)
            v[i] = nt_load(&xp[(size_t)i * D4]);

#pragma unroll
        for (int wi = 0; wi < CHW; ++wi) {
            float4 w = f4add(f4add(v[3 * wi], v[3 * wi + 1]), v[3 * wi + 2]);
            float4 wm = make_float4(w.x * (1.f / 3.f), w.y * (1.f / 3.f),
                                    w.z * (1.f / 3.f), w.w * (1.f / 3.f));
            nt_store(wm, &opb[(size_t)(2 * (k0 + wi) + 1) * D4]);
        }

        float4 run = z4;
#pragma unroll
        for (int i = 0; i < CHR; ++i) {
            rl[(size_t)i * D4] = run;
            run = f4add(run, v[i]);
        }
        P4[((size_t)b * NCH + ch) * D4 + t] = run;   // chunk total
    }

    cg::this_grid().sync();

    // ---------------- Phase 2: chunk-prefix scan (blocks bx<8) ----------
    __shared__ float4 part[8][33];
    if (bx < 8) {
        const int cw  = t & 31;            // f4-col within tile
        const int seg = t >> 5;            // 0..7 -> 16 chunks each
        const int col = bx * 32 + cw;

        const float4* p = P4 + (size_t)b * NCH * D4 + col;
        float4 v2[16];
        float4 sum = z4;
#pragma unroll
        for (int i = 0; i < 16; ++i) {
            v2[i] = p[(size_t)(seg * 16 + i) * D4];
            sum = f4add(sum, v2[i]);
        }
        part[seg][cw] = sum;
        __syncthreads();
        if (t < 32) {
            float4 run = z4;
#pragma unroll
            for (int s = 0; s < 8; ++s) {
                float4 t2 = part[s][t];
                part[s][t] = run;
                run = f4add(run, t2);
            }
        }
        __syncthreads();
        float4 run = part[seg][cw];
        float4* o = O4 + (size_t)b * (NCH + 1) * D4 + col;
#pragma unroll
        for (int i = 0; i < 16; ++i) {
            o[(size_t)(seg * 16 + i) * D4] = run;
            run = f4add(run, v2[i]);
        }
        if (seg == 7) o[(size_t)NCH * D4] = run;   // grand total = c[N]
    }

    cg::this_grid().sync();

    // ---------------- Phase 3: 16 steps/block, 4 groups of 4 ------------
    const float4* rb = R4 + (size_t)b * Nn * D4 + t;
    const float4* oc = O4 + (size_t)b * (NCH + 1) * D4 + t;
    for (int g = 0; g < 4; ++g) {
        const int kbase = bx * 16 + g * 4;
        const int* gp = graph + ((size_t)(b * STEPS + kbase)) * 2;
        const int4 ga = *reinterpret_cast<const int4*>(gp);
        const int4 gb2 = *reinterpret_cast<const int4*>(gp + 4);
        const int sA[4] = {ga.x, ga.z, gb2.x, gb2.z};
        const int eA[4] = {ga.y, ga.w, gb2.y, gb2.w};

        float4 o1[4], r1[4], o2[4], r2[4];
        int ieA[4];
#pragma unroll
        for (int u = 0; u < 4; ++u) {
            int s  = sA[u];
            o1[u] = oc[(size_t)(s / CHR) * D4];     // hot 4.2 MB table
            r1[u] = rb[(size_t)s * D4];             // random 4 KB row

            int ie = eA[u] + 1;      ieA[u] = ie;   // 1..3072
            o2[u] = oc[(size_t)(ie / CHR) * D4];    // O[128] = grand total
            int rc = ie < Nn ? ie : Nn - 1;         // clamp: always valid
            r2[u] = rb[(size_t)rc * D4];
        }
#pragma unroll
        for (int u = 0; u < 4; ++u) {
            float4 cs = f4add(o1[u], r1[u]);
            float4 ce = f4add(o2[u], f4sel(ieA[u] < Nn, r2[u], z4));

            float inv = 1.f / (float)(eA[u] - sA[u] + 1);
            float4 res = make_float4((ce.x - cs.x) * inv + EPS,
                                     (ce.y - cs.y) * inv + EPS,
                                     (ce.z - cs.z) * inv + EPS,
                                     (ce.w - cs.w) * inv + EPS);
            nt_store(res, &opb[(size_t)(2 * (kbase + u)) * D4]);
        }
    }
}

extern "C" void kernel_launch(void* const* d_in, const int* in_sizes, int n_in,
                              void* d_out, int out_size, void* d_ws, size_t ws_size,
                              hipStream_t stream) {
    const float* x     = (const float*)d_in[0];
    const int*   graph = (const int*)d_in[1];
    float*       out   = (float*)d_out;

    float* R = (float*)d_ws;
    float* P = R + R_E;
    float* O = P + P_E;

    const float4* x4   = (const float4*)x;
    float4*       out4 = (float4*)out;
    float4*       R4   = (float4*)R;
    float4*       P4   = (float4*)P;
    float4*       O4   = (float4*)O;

    void* args[] = {(void*)&x4, (void*)&graph, (void*)&out4,
                    (void*)&R4, (void*)&P4, (void*)&O4};
    hipLaunchCooperativeKernel((const void*)fused, dim3(64, Bdim), dim3(256),
                               args, 0, stream);
}

// Round 5
// 193.163 us; speedup vs baseline: 1.7997x; 1.7997x over previous
//
#include <hip/hip_runtime.h>

// GraphPooling: B=8, N=3072, D=1024, POOL=3, steps=1024
//  out[b, 2k,   d] = (sum x[b, s..e, d]) / (e-s+1) + 0.006
//  out[b, 2k+1, d] = mean(x[b, 3k:3k+3, d])
//
// Round-12: event-driven snapshot scheme (no random reads anywhere).
//  R4 fused-kernel counters: whole algorithm = 283 MB HBM (44 us @ 6.4TB/s),
//  VALUBusy 1.4%, occupancy-capped -> everything is latency, and the R
//  buffer's random reads were already L3-hits. So: stop materializing R and
//  gathering it; PUSH the needed prefix rows into a dense per-step buffer.
//   K0: bucket the 2 query rows of each step (s, e+1) into per-row event
//       lists (8 blocks, LDS atomics).
//   K1: per-chunk scan: x (nt) -> window means (odd out rows), within-chunk
//       exclusive prefix; at each row with events, store prefix to T[trow].
//       Chunk total -> P.  (No 96 MB R write.)
//   K2: scan P -> exclusive chunk prefix O (proven version).
//   K4: out[2k] = (O[ch(e+1)] + T[2k+1] - O[ch(s)] - T[2k]) * inv + EPS.
//       T rows are read SEQUENTIALLY (rows 2k..2k+7 per block) - coalesced,
//       L3-hot. Same summation order as R3 -> identical numerics.

constexpr int Bdim  = 8;
constexpr int Nn    = 3072;
constexpr int Dd    = 1024;
constexpr int STEPS = 1024;   // windows
constexpr int CHW   = 8;      // windows per chunk
constexpr int CHR   = 24;     // rows per chunk
constexpr int NCH   = 128;    // STEPS / CHW
constexpr int KT    = 4;      // steps per K4 block
constexpr int NKT   = 256;    // STEPS / KT
constexpr int D4    = Dd / 4; // 256 float4 per row
constexpr int RCAP  = 12;     // max events per row (Poisson lam=0.67 -> 12 is ~1e-11 tail)
constexpr float EPS = 0.006f;

constexpr size_t T_E = (size_t)Bdim * 2 * STEPS * Dd;     // 64 MB (floats)
constexpr size_t P_E = (size_t)Bdim * NCH * Dd;           //  4 MB
constexpr size_t O_E = (size_t)Bdim * (NCH + 1) * Dd;     //  4.2 MB

typedef float nat_f4 __attribute__((ext_vector_type(4)));

__device__ __forceinline__ float4 f4add(float4 a, float4 b) {
    return make_float4(a.x + b.x, a.y + b.y, a.z + b.z, a.w + b.w);
}

__device__ __forceinline__ float4 f4sel(bool c, float4 a, float4 b) {
    return make_float4(c ? a.x : b.x, c ? a.y : b.y,
                       c ? a.z : b.z, c ? a.w : b.w);
}

__device__ __forceinline__ void nt_store(float4 v, float4* p) {
    nat_f4 nv = {v.x, v.y, v.z, v.w};
    __builtin_nontemporal_store(nv, reinterpret_cast<nat_f4*>(p));
}

__device__ __forceinline__ float4 nt_load(const float4* p) {
    nat_f4 nv = __builtin_nontemporal_load(reinterpret_cast<const nat_f4*>(p));
    return make_float4(nv.x, nv.y, nv.z, nv.w);
}

// ---------------- K0: bucket query rows -> per-row event lists ----------
//  event row s   gets trow 2k   (start snapshot)
//  event row e+1 gets trow 2k+1 (end snapshot), skipped if e+1 == Nn
__global__ __launch_bounds__(256)
void k0_bucket(const int* __restrict__ graph, int* __restrict__ rowcnt,
               int* __restrict__ evrow) {
    const int b = blockIdx.x;
    __shared__ int cnt[Nn];                      // 12 KB
    for (int i = threadIdx.x; i < Nn; i += 256) cnt[i] = 0;
    __syncthreads();
    for (int k = threadIdx.x; k < STEPS; k += 256) {
        const int2 se = *reinterpret_cast<const int2*>(
            graph + ((size_t)(b * STEPS + k)) * 2);
        const int s  = se.x;
        const int ie = se.y + 1;
        int sl = atomicAdd(&cnt[s], 1);
        if (sl < RCAP)
            evrow[((size_t)b * Nn + s) * RCAP + sl] = 2 * k;
        if (ie < Nn) {
            int sl2 = atomicAdd(&cnt[ie], 1);
            if (sl2 < RCAP)
                evrow[((size_t)b * Nn + ie) * RCAP + sl2] = 2 * k + 1;
        }
    }
    __syncthreads();
    for (int i = threadIdx.x; i < Nn; i += 256)
        rowcnt[(size_t)b * Nn + i] = min(cnt[i], RCAP);
}

// ---------------- K1: scan chunk, window means, push snapshots ----------
__global__ __launch_bounds__(256)
void k1_scan(const float4* __restrict__ x4, float4* __restrict__ out4,
             float4* __restrict__ T4, float4* __restrict__ P4,
             const int* __restrict__ rowcnt, const int* __restrict__ evrow) {
    const int t  = threadIdx.x;          // float4 column 0..255
    const int ch = blockIdx.x;           // 0..127
    const int b  = blockIdx.y;           // 0..7
    const int k0 = ch * CHW;
    const int r0 = ch * CHR;
    const float4 z4 = make_float4(0.f, 0.f, 0.f, 0.f);

    const float4* xp = x4   + ((size_t)(b * Nn + r0)) * D4 + t;
    float4*       op = out4 + ((size_t)b * 2 * STEPS) * D4 + t;
    float4*       Tb = T4   + ((size_t)b * 2 * STEPS) * D4 + t;
    const int*    rc = rowcnt + (size_t)b * Nn + r0;
    const int*    ev = evrow + ((size_t)b * Nn + r0) * RCAP;

    // phase A: issue all 24 x loads (nt: streamed once, proven faster)
    float4 v[CHR];
#pragma unroll
    for (int i = 0; i < CHR; ++i)
        v[i] = nt_load(&xp[(size_t)i * D4]);

    // phase B: window means -> odd output rows
#pragma unroll
    for (int wi = 0; wi < CHW; ++wi) {
        float4 w = f4add(f4add(v[3 * wi], v[3 * wi + 1]), v[3 * wi + 2]);
        float4 wm = make_float4(w.x * (1.f / 3.f), w.y * (1.f / 3.f),
                                w.z * (1.f / 3.f), w.w * (1.f / 3.f));
        nt_store(wm, &op[(size_t)(2 * (k0 + wi) + 1) * D4]);
    }

    // phase C: within-chunk exclusive prefix; push snapshots at event rows
    float4 run = z4;
#pragma unroll
    for (int j = 0; j < CHR; ++j) {
        const int nj = rc[j];                        // uniform (L2-hot)
        for (int q = 0; q < nj; ++q) {               // usually 0 or 1
            const int trow = ev[j * RCAP + q];       // uniform
            Tb[(size_t)trow * D4] = run;             // coalesced 4 KB row
        }
        run = f4add(run, v[j]);
    }
    P4[((size_t)b * NCH + ch) * D4 + t] = run;       // chunk total
}

// ---------------- K2: 2-level scan of chunk totals -> exclusive prefix O ----
__global__ __launch_bounds__(256)
void k2_chscan(const float4* __restrict__ P4, float4* __restrict__ O4) {
    __shared__ float4 part[8][33];
    const int cw  = threadIdx.x & 31;          // f4-col within tile
    const int seg = threadIdx.x >> 5;          // 0..7 -> 16 chunks each
    const int col = blockIdx.x * 32 + cw;
    const int b   = blockIdx.y;

    const float4* p = P4 + (size_t)b * NCH * D4 + col;
    float4 v[16];
    float4 sum = make_float4(0.f, 0.f, 0.f, 0.f);
#pragma unroll
    for (int i = 0; i < 16; ++i) {
        v[i] = p[(size_t)(seg * 16 + i) * D4];
        sum = f4add(sum, v[i]);
    }
    part[seg][cw] = sum;
    __syncthreads();
    if (threadIdx.x < 32) {
        float4 run = make_float4(0.f, 0.f, 0.f, 0.f);
#pragma unroll
        for (int s = 0; s < 8; ++s) {
            float4 t2 = part[s][threadIdx.x];
            part[s][threadIdx.x] = run;
            run = f4add(run, t2);
        }
    }
    __syncthreads();
    float4 run = part[seg][cw];
    float4* o = O4 + (size_t)b * (NCH + 1) * D4 + col;
#pragma unroll
    for (int i = 0; i < 16; ++i) {
        o[(size_t)(seg * 16 + i) * D4] = run;
        run = f4add(run, v[i]);
    }
    if (seg == 7) o[(size_t)NCH * D4] = run;   // grand total = c[N]
}

// ---------------- K4: streaming combine ----------------
//  out[2k] = (O[ch(e+1)] + T[2k+1] - O[ch(s)] - T[2k]) * inv + EPS
__global__ __launch_bounds__(256)
void k4_combine(const float4* __restrict__ T4, const float4* __restrict__ O4,
                const int* __restrict__ graph, float4* __restrict__ out4) {
    const int t  = threadIdx.x;
    const int kt = blockIdx.x;                 // 0..255
    const int b  = blockIdx.y;

    const int* gp = graph + ((size_t)(b * STEPS + kt * KT)) * 2;
    const int4 ga = *reinterpret_cast<const int4*>(gp);
    const int4 gb = *reinterpret_cast<const int4*>(gp + 4);
    const int sA[KT] = {ga.x, ga.z, gb.x, gb.z};
    const int eA[KT] = {ga.y, ga.w, gb.y, gb.w};

    const float4* Tb = T4 + (size_t)b * 2 * STEPS * D4 + t;
    const float4* oc = O4 + (size_t)b * (NCH + 1) * D4 + t;
    float4*       ob = out4 + (size_t)b * 2 * STEPS * D4 + t;

    // ---- issue ALL loads before any combine ----
    float4 ts[KT], te[KT], o1[KT], o2[KT];
    int ieA[KT];
    const float4 tot = oc[(size_t)NCH * D4];   // grand total row (hot)
#pragma unroll
    for (int u = 0; u < KT; ++u) {
        const int k = kt * KT + u;
        ts[u] = Tb[(size_t)(2 * k) * D4];      // sequential streaming rows
        te[u] = Tb[(size_t)(2 * k + 1) * D4];
        const int s = sA[u];
        const int ie = eA[u] + 1;  ieA[u] = ie;            // 1..3072
        o1[u] = oc[(size_t)(s / CHR) * D4];                // hot 4.2 MB table
        const int c2 = ie < Nn ? ie / CHR : 0;             // clamp (sel'd away)
        o2[u] = oc[(size_t)c2 * D4];
    }

    // ---- combine + store ----
#pragma unroll
    for (int u = 0; u < KT; ++u) {
        float4 cs = f4add(o1[u], ts[u]);
        float4 ce = f4sel(ieA[u] < Nn, f4add(o2[u], te[u]), tot);

        float inv = 1.f / (float)(eA[u] - sA[u] + 1);
        float4 res = make_float4((ce.x - cs.x) * inv + EPS,
                                 (ce.y - cs.y) * inv + EPS,
                                 (ce.z - cs.z) * inv + EPS,
                                 (ce.w - cs.w) * inv + EPS);
        const int k = kt * KT + u;
        nt_store(res, &ob[(size_t)(2 * k) * D4]);   // even output row
    }
}

extern "C" void kernel_launch(void* const* d_in, const int* in_sizes, int n_in,
                              void* d_out, int out_size, void* d_ws, size_t ws_size,
                              hipStream_t stream) {
    const float* x     = (const float*)d_in[0];
    const int*   graph = (const int*)d_in[1];
    float*       out   = (float*)d_out;

    float* T = (float*)d_ws;
    float* P = T + T_E;
    float* O = P + P_E;
    int*   rowcnt = (int*)(O + O_E);
    int*   evrow  = rowcnt + (size_t)Bdim * Nn;

    k0_bucket<<<dim3(Bdim), 256, 0, stream>>>(graph, rowcnt, evrow);
    dim3 g1(NCH, Bdim);          // (128, 8) = 1024 blocks
    k1_scan<<<g1, 256, 0, stream>>>((const float4*)x, (float4*)out,
                                    (float4*)T, (float4*)P, rowcnt, evrow);
    dim3 g2(D4 / 32, Bdim);      // (8, 8) = 64 blocks
    k2_chscan<<<g2, 256, 0, stream>>>((const float4*)P, (float4*)O);
    dim3 g4(NKT, Bdim);          // (256, 8) = 2048 blocks
    k4_combine<<<g4, 256, 0, stream>>>((const float4*)T, (const float4*)O,
                                       graph, (float4*)out);
}